// Round 5
// baseline (4891.050 us; speedup 1.0000x reference)
//
#include <hip/hip_runtime.h>
#include <hip/hip_bf16.h>
#include <math.h>

#define NB 32
#define NS 4096
#define ND 256
#define NHOP 10
#define EPSBN 1e-5f
#define NEG_SLOPE 0.01f

typedef _Float16 half8 __attribute__((ext_vector_type(8)));
typedef float floatx4 __attribute__((ext_vector_type(4)));

// ---------------- workspace layout (bytes) ----------------
static const size_t SZ_PAIR = (size_t)NB*NS*ND*2;            // 67,108,864 (ushort plane)
static const size_t OFF_HI0 = 0;
static const size_t OFF_LO0 = OFF_HI0 + SZ_PAIR;
static const size_t OFF_HI1 = OFF_LO0 + SZ_PAIR;
static const size_t OFF_LO1 = OFF_HI1 + SZ_PAIR;
static const size_t OFF_E   = OFF_LO1 + SZ_PAIR;
static const size_t OFF_Q   = OFF_E   + (size_t)NB*NS*4;
static const size_t OFF_OP  = OFF_Q   + (size_t)NB*ND*4;
static const size_t OFF_WPH = OFF_OP  + (size_t)NB*32*ND*4;
static const size_t OFF_WPL = OFF_WPH + (size_t)1280*ND*2;
static const size_t OFF_SC  = OFF_WPL + (size_t)1280*ND*2;
static const size_t OFF_SH  = OFF_SC  + (size_t)ND*4;
static const size_t OFF_RM  = OFF_SH  + (size_t)ND*4;
static const size_t OFF_RI  = OFF_RM  + (size_t)NB*4;
static const size_t OFF_HA  = OFF_RI  + (size_t)NB*4;
static const size_t OFF_RU  = OFF_HA  + (size_t)NB*4;

__device__ __forceinline__ float uh2f(ushort u) {
    _Float16 h = __builtin_bit_cast(_Float16, u);
    return (float)h;
}
__device__ __forceinline__ ushort f2uh(float f) {
    _Float16 h = (_Float16)f;
    return __builtin_bit_cast(ushort, h);
}
__device__ __forceinline__ void load_lds16(const void* g, void* l) {
    __builtin_amdgcn_global_load_lds((const __attribute__((address_space(1))) void*)g,
                                     (__attribute__((address_space(3))) void*)l, 16, 0, 0);
}

// ---------------- split fp32 x -> (hi, lo) f16 planes ----------------
__global__ void k_split(const float* __restrict__ x, ushort* __restrict__ hi, ushort* __restrict__ lo)
{
    size_t i = ((size_t)blockIdx.x * 256 + threadIdx.x) * 4;
    float4 v = *(const float4*)(x + i);
    ushort4 h, l;
    h.x = f2uh(v.x); l.x = f2uh(v.x - uh2f(h.x));
    h.y = f2uh(v.y); l.y = f2uh(v.y - uh2f(h.y));
    h.z = f2uh(v.z); l.z = f2uh(v.z - uh2f(h.z));
    h.w = f2uh(v.w); l.w = f2uh(v.w - uh2f(h.w));
    *(ushort4*)(hi + i) = h;
    *(ushort4*)(lo + i) = l;
}

// ---------------- init: pack W (hi/lo, [dout][t][din]), BN affine, q, halted, running ----
__global__ void k_init(const float* __restrict__ conv_w, const float* __restrict__ conv_b,
                       const float* __restrict__ bn_gamma, const float* __restrict__ bn_beta,
                       const float* __restrict__ bn_mean, const float* __restrict__ bn_var,
                       const float* __restrict__ query,
                       ushort* __restrict__ Wph, ushort* __restrict__ Wpl,
                       float* __restrict__ scale, float* __restrict__ shift,
                       float* __restrict__ q, int* __restrict__ halted, int* __restrict__ running)
{
    int idx = blockIdx.x * 256 + threadIdx.x;
    if (idx < 1280 * 256) {
        int din  = idx & 255;
        int r    = idx >> 8;
        int t    = r % 5;
        int dout = r / 5;
        float w = conv_w[dout * 1280 + din * 5 + t];
        ushort wh = f2uh(w);
        Wph[idx] = wh;
        Wpl[idx] = f2uh(w - uh2f(wh));
    }
    if (idx < NB * ND) q[idx] = query[idx & (ND - 1)];
    if (idx < ND) {
        float a = bn_gamma[idx] * rsqrtf(bn_var[idx] + EPSBN);
        scale[idx] = a;
        shift[idx] = (conv_b[idx] - bn_mean[idx]) * a + bn_beta[idx];
    }
    if (idx < NB) halted[idx] = 0;
    if (idx == 0) running[0] = 1;
}

// ---------------- K1: e[b,s] = dot(x[b,s,:], q[b,:]) (hi+lo), mask -> -inf ----------------
__global__ void k_attn(const ushort* __restrict__ xhi, const ushort* __restrict__ xlo,
                       const float* __restrict__ q, const int* __restrict__ mask,
                       float* __restrict__ e)
{
    int row  = blockIdx.x * 4 + (threadIdx.x >> 6);
    int lane = threadIdx.x & 63;
    int b    = row >> 12;
    size_t o = (size_t)row * ND + (lane << 2);
    ushort4 hv = *(const ushort4*)(xhi + o);
    ushort4 lv = *(const ushort4*)(xlo + o);
    float4 qv = *(const float4*)(q + b * ND + (lane << 2));
    float v = (uh2f(hv.x) + uh2f(lv.x)) * qv.x
            + (uh2f(hv.y) + uh2f(lv.y)) * qv.y
            + (uh2f(hv.z) + uh2f(lv.z)) * qv.z
            + (uh2f(hv.w) + uh2f(lv.w)) * qv.w;
    #pragma unroll
    for (int off = 32; off; off >>= 1) v += __shfl_xor(v, off, 64);
    if (lane == 0) e[row] = (mask[row] != 0) ? -INFINITY : v;
}

// ---------------- K2: per-b softmax stats; block0 computes running flag ----------------
__global__ void k_stats(const float* __restrict__ e, float* __restrict__ rmax,
                        float* __restrict__ rinv, const int* __restrict__ halted,
                        int* __restrict__ running)
{
    __shared__ float sm[256];
    int b = blockIdx.x, tid = threadIdx.x;
    float m = -INFINITY;
    for (int s = tid; s < NS; s += 256) m = fmaxf(m, e[b * NS + s]);
    sm[tid] = m; __syncthreads();
    for (int off = 128; off; off >>= 1) {
        if (tid < off) sm[tid] = fmaxf(sm[tid], sm[tid + off]);
        __syncthreads();
    }
    float bm = sm[0]; __syncthreads();
    float sum = 0.f;
    for (int s = tid; s < NS; s += 256) sum += expf(e[b * NS + s] - bm);
    sm[tid] = sum; __syncthreads();
    for (int off = 128; off; off >>= 1) {
        if (tid < off) sm[tid] += sm[tid + off];
        __syncthreads();
    }
    if (tid == 0) { rmax[b] = bm; rinv[b] = 1.0f / sm[0]; }
    if (b == 0 && tid < 64) {
        unsigned long long any = __ballot(tid < NB && halted[tid] != 0);
        if (tid == 0) running[0] = (any == 0ull) ? 1 : 0;
    }
}

// ---------------- K3: conv via split-f16 MFMA + BN + leakyReLU + mask + fused o-partials --
// block 512 thr = 8 waves; tile BM=128 rows x BN=256 douts.
// wave w: rows [(w>>2)*64, +64), douts [(w&3)*64, +64); M_rep=4, N_rep=4 of 16x16x32.
// Register diet: 3-pass MFMA per (t,ds) so only ONE 4-entry B-frag array is live;
// W offsets computed inline (uniform parts -> SGPR). Target: acc 64 AGPR + <64 VGPR.
__global__ __launch_bounds__(512, 4) void k_conv(
    const ushort* __restrict__ xhi, const ushort* __restrict__ xlo,
    ushort* __restrict__ ohi, ushort* __restrict__ olo,
    const ushort* __restrict__ Wph, const ushort* __restrict__ Wpl,
    const float* __restrict__ scale, const float* __restrict__ shift,
    const int* __restrict__ maskp, const float* __restrict__ e,
    const float* __restrict__ rmax, const float* __restrict__ rinv,
    float* __restrict__ o_part, const int* __restrict__ running)
{
    const int bb  = blockIdx.x >> 5;
    const int s0  = (blockIdx.x & 31) << 7;
    const int tid = threadIdx.x;

    if (running[0] == 0) {   // frozen: copy state
        const size_t base = ((size_t)bb * NS + s0) * ND;
        const uint4* sh_ = (const uint4*)(xhi + base);
        const uint4* sl_ = (const uint4*)(xlo + base);
        uint4* dh = (uint4*)(ohi + base);
        uint4* dl = (uint4*)(olo + base);
        for (int i = tid; i < 4096; i += 512) { dh[i] = sh_[i]; dl[i] = sl_[i]; }
        return;
    }

    __shared__ __align__(16) ushort Ah[8704];   // 136 rows x 64 din (rows s0-2 .. s0+133)
    __shared__ __align__(16) ushort Al[8704];
    __shared__ float p_lds[128];
    __shared__ float o_red[2][256];

    const int lane  = tid & 63;
    const int wid   = tid >> 6;
    const int mlane = lane & 15;       // C col / A row lane
    const int klane = lane >> 4;       // k-block
    const int wrow0 = (wid >> 2) << 6; // wave's row base within tile
    const int dbase = (wid & 3) << 6;  // wave's dout base

    // probs for this block's 128 rows (softmax of e over current xc)
    if (tid < 128) {
        float ev = e[bb * NS + s0 + tid];
        p_lds[tid] = expf(ev - rmax[bb]) * rinv[bb];
    }

    floatx4 acc[4][4];
    #pragma unroll
    for (int m = 0; m < 4; ++m)
        #pragma unroll
        for (int n = 0; n < 4; ++n) acc[m][n] = (floatx4){0.f, 0.f, 0.f, 0.f};

    const bool ztop = (s0 == 0), zbot = (s0 == NS - 128);

    for (int kc = 0; kc < 4; ++kc) {
        __syncthreads();   // protect LDS reuse across chunks
        // stage 136 rows x 64 din, both planes; LDS linear dest, pre-swizzled global src
        for (int i0 = tid; i0 < 1088; i0 += 512) {
            int lrow = i0 >> 3;
            int grp  = (i0 & 7) ^ (lrow & 7);
            int srow = s0 - 2 + lrow;
            srow = srow < 0 ? 0 : (srow > NS - 1 ? NS - 1 : srow);
            size_t go = ((size_t)bb * NS + srow) * ND + (kc << 6) + (grp << 3);
            load_lds16(xhi + go, &Ah[i0 * 8]);
            load_lds16(xlo + go, &Al[i0 * 8]);
        }
        __syncthreads();   // compiler drains vmcnt before barrier
        if (ztop || zbot) {
            if (ztop && tid < 32) {   // rows 0,1 <- global rows -2,-1 := 0
                *(unsigned long long*)(&Ah[tid * 4]) = 0ull;
                *(unsigned long long*)(&Al[tid * 4]) = 0ull;
            }
            if (zbot && tid < 32) {   // rows 130,131 <- global rows 4096,4097 := 0
                *(unsigned long long*)(&Ah[8320 + tid * 4]) = 0ull;
                *(unsigned long long*)(&Al[8320 + tid * 4]) = 0ull;
            }
            __syncthreads();
        }

        #pragma unroll
        for (int t = 0; t < 5; ++t) {
            #pragma unroll
            for (int ds_ = 0; ds_ < 2; ++ds_) {
                const int din = (kc << 6) + (ds_ << 5) + (klane << 3);
                const int gb  = (ds_ << 2) + klane;   // 16B group within 64-din row
                half8 bf[4];

                // ---- passes 1+2: W_hi against A_hi then A_lo ----
                #pragma unroll
                for (int n = 0; n < 4; ++n) {
                    size_t wo = ((size_t)((dbase + (n << 4) + mlane) * 5 + t) << 8) + din;
                    bf[n] = *(const half8*)(Wph + wo);
                }
                #pragma unroll
                for (int m = 0; m < 4; ++m) {
                    int row = wrow0 + (m << 4) + mlane + t;      // lds row = out_row + t
                    int off = (row << 7) + ((gb ^ (row & 7)) << 4);
                    half8 ah = *(const half8*)((const char*)Ah + off);
                    #pragma unroll
                    for (int n = 0; n < 4; ++n)
                        acc[m][n] = __builtin_amdgcn_mfma_f32_16x16x32_f16(ah, bf[n], acc[m][n], 0, 0, 0);
                }
                #pragma unroll
                for (int m = 0; m < 4; ++m) {
                    int row = wrow0 + (m << 4) + mlane + t;
                    int off = (row << 7) + ((gb ^ (row & 7)) << 4);
                    half8 al = *(const half8*)((const char*)Al + off);
                    #pragma unroll
                    for (int n = 0; n < 4; ++n)
                        acc[m][n] = __builtin_amdgcn_mfma_f32_16x16x32_f16(al, bf[n], acc[m][n], 0, 0, 0);
                }

                // ---- pass 3: W_lo against A_hi ----
                #pragma unroll
                for (int n = 0; n < 4; ++n) {
                    size_t wo = ((size_t)((dbase + (n << 4) + mlane) * 5 + t) << 8) + din;
                    bf[n] = *(const half8*)(Wpl + wo);
                }
                #pragma unroll
                for (int m = 0; m < 4; ++m) {
                    int row = wrow0 + (m << 4) + mlane + t;
                    int off = (row << 7) + ((gb ^ (row & 7)) << 4);
                    half8 ah = *(const half8*)((const char*)Ah + off);
                    #pragma unroll
                    for (int n = 0; n < 4; ++n)
                        acc[m][n] = __builtin_amdgcn_mfma_f32_16x16x32_f16(ah, bf[n], acc[m][n], 0, 0, 0);
                }
            }
        }
    }

    // epilogue: BN + leakyReLU + mask, emit split f16, accumulate o partials
    float sc[4], sh[4];
    #pragma unroll
    for (int n = 0; n < 4; ++n) {
        int d = dbase + (n << 4) + mlane;
        sc[n] = scale[d]; sh[n] = shift[d];
    }
    float osum[4] = {0.f, 0.f, 0.f, 0.f};
    #pragma unroll
    for (int m = 0; m < 4; ++m) {
        #pragma unroll
        for (int r = 0; r < 4; ++r) {
            int prow = wrow0 + (m << 4) + (klane << 2) + r;  // C/D: row=(lane>>4)*4+reg
            int s = s0 + prow;
            int mk = maskp[bb * NS + s];
            float po = p_lds[prow];
            size_t ob = ((size_t)bb * NS + s) * ND + dbase + mlane;
            #pragma unroll
            for (int n = 0; n < 4; ++n) {
                float v = acc[m][n][r] * sc[n] + sh[n];
                v = (v >= 0.f) ? v : NEG_SLOPE * v;
                v = mk ? 0.f : v;
                ushort hw = f2uh(v);
                ushort lw = f2uh(v - uh2f(hw));
                ohi[ob + (size_t)(n << 4)] = hw;
                olo[ob + (size_t)(n << 4)] = lw;
                osum[n] += po * v;
            }
        }
    }
    // reduce osum over klane (lane bits 4,5), then combine wave groups via LDS
    #pragma unroll
    for (int n = 0; n < 4; ++n) {
        osum[n] += __shfl_xor(osum[n], 16, 64);
        osum[n] += __shfl_xor(osum[n], 32, 64);
    }
    if (lane < 16) {
        #pragma unroll
        for (int n = 0; n < 4; ++n)
            o_red[wid >> 2][dbase + (n << 4) + mlane] = osum[n];
    }
    __syncthreads();
    if (tid < 256)
        o_part[((size_t)bb * 32 + (s0 >> 7)) * ND + tid] = o_red[0][tid] + o_red[1][tid];
}

// ---------------- K5: reduce o, halt logits, gated q/halted update ----------------
__global__ void k_update(const float* __restrict__ o_part, float* __restrict__ q,
                         const float* __restrict__ halt_w, const float* __restrict__ halt_b,
                         int* __restrict__ halted, const int* __restrict__ running)
{
    int b = blockIdx.x, d = threadIdx.x;
    __shared__ float sh0[256], sh1[256];
    float o = 0.f;
    #pragma unroll
    for (int ch = 0; ch < 32; ++ch) o += o_part[(b * 32 + ch) * ND + d];
    float qd = q[b * ND + d];
    float s1 = o + qd;
    sh0[d] = s1 * halt_w[d];
    sh1[d] = s1 * halt_w[ND + d];
    __syncthreads();
    for (int off = 128; off; off >>= 1) {
        if (d < off) { sh0[d] += sh0[d + off]; sh1[d] += sh1[d + off]; }
        __syncthreads();
    }
    float l0 = sh0[0] + halt_b[0];
    float l1 = sh1[0] + halt_b[1];
    int hOld = halted[b];
    if (running[0]) {
        q[b * ND + d] = o + qd * (1.f - (float)hOld);
        if (d == 0) halted[b] = hOld | ((l1 > l0) ? 1 : 0);
    }
}

// ---------------- K6: q -> d_out ----------------
__global__ void k_copyout(const float* __restrict__ q, float* __restrict__ out)
{
    int idx = blockIdx.x * 256 + threadIdx.x;
    if (idx < NB * ND) out[idx] = q[idx];
}

extern "C" void kernel_launch(void* const* d_in, const int* in_sizes, int n_in,
                              void* d_out, int out_size, void* d_ws, size_t ws_size,
                              hipStream_t stream)
{
    const float* x        = (const float*)d_in[0];
    const int*   mask     = (const int*)  d_in[1];
    const float* query    = (const float*)d_in[2];
    const float* conv_w   = (const float*)d_in[3];
    const float* conv_b   = (const float*)d_in[4];
    const float* bn_gamma = (const float*)d_in[5];
    const float* bn_beta  = (const float*)d_in[6];
    const float* bn_mean  = (const float*)d_in[7];
    const float* bn_var   = (const float*)d_in[8];
    const float* halt_w   = (const float*)d_in[9];
    const float* halt_b   = (const float*)d_in[10];

    char* ws = (char*)d_ws;
    ushort* hi0 = (ushort*)(ws + OFF_HI0);
    ushort* lo0 = (ushort*)(ws + OFF_LO0);
    ushort* hi1 = (ushort*)(ws + OFF_HI1);
    ushort* lo1 = (ushort*)(ws + OFF_LO1);
    float* ebuf = (float*)(ws + OFF_E);
    float* qbuf = (float*)(ws + OFF_Q);
    float* opart= (float*)(ws + OFF_OP);
    ushort* Wph = (ushort*)(ws + OFF_WPH);
    ushort* Wpl = (ushort*)(ws + OFF_WPL);
    float* scale= (float*)(ws + OFF_SC);
    float* shift= (float*)(ws + OFF_SH);
    float* rmax = (float*)(ws + OFF_RM);
    float* rinv = (float*)(ws + OFF_RI);
    int* halted = (int*)  (ws + OFF_HA);
    int* runf   = (int*)  (ws + OFF_RU);

    k_init<<<1280, 256, 0, stream>>>(conv_w, conv_b, bn_gamma, bn_beta, bn_mean, bn_var,
                                     query, Wph, Wpl, scale, shift, qbuf, halted, runf);
    k_split<<<32768, 256, 0, stream>>>(x, hi0, lo0);

    for (int h = 0; h < NHOP; ++h) {
        const ushort* ih = (h & 1) ? hi1 : hi0;
        const ushort* il = (h & 1) ? lo1 : lo0;
        ushort* oh = (h & 1) ? hi0 : hi1;
        ushort* ol = (h & 1) ? lo0 : lo1;

        k_attn  <<<NB * NS / 4, 256, 0, stream>>>(ih, il, qbuf, mask, ebuf);
        k_stats <<<NB, 256, 0, stream>>>(ebuf, rmax, rinv, halted, runf);
        k_conv  <<<NB * 32, 512, 0, stream>>>(ih, il, oh, ol, Wph, Wpl, scale, shift,
                                              mask, ebuf, rmax, rinv, opart, runf);
        k_update<<<NB, 256, 0, stream>>>(opart, qbuf, halt_w, halt_b, halted, runf);
    }

    k_copyout<<<NB, 256, 0, stream>>>(qbuf, (float*)d_out);
}

// Round 6
// 2615.660 us; speedup vs baseline: 1.8699x; 1.8699x over previous
//
#include <hip/hip_runtime.h>
#include <hip/hip_bf16.h>
#include <math.h>

#define NB 32
#define NS 4096
#define ND 256
#define NHOP 10
#define EPSBN 1e-5f
#define NEG_SLOPE 0.01f

typedef _Float16 half8 __attribute__((ext_vector_type(8)));
typedef float floatx4 __attribute__((ext_vector_type(4)));

// ---------------- workspace layout (bytes) ----------------
static const size_t SZ_PAIR = (size_t)NB*NS*ND*2;            // 67,108,864 (ushort plane)
static const size_t OFF_HI0 = 0;
static const size_t OFF_LO0 = OFF_HI0 + SZ_PAIR;
static const size_t OFF_HI1 = OFF_LO0 + SZ_PAIR;
static const size_t OFF_LO1 = OFF_HI1 + SZ_PAIR;
static const size_t OFF_E   = OFF_LO1 + SZ_PAIR;
static const size_t OFF_Q   = OFF_E   + (size_t)NB*NS*4;
static const size_t OFF_OP  = OFF_Q   + (size_t)NB*ND*4;
static const size_t OFF_WPH = OFF_OP  + (size_t)NB*32*ND*4;
static const size_t OFF_WPL = OFF_WPH + (size_t)1280*ND*2;
static const size_t OFF_SC  = OFF_WPL + (size_t)1280*ND*2;
static const size_t OFF_SH  = OFF_SC  + (size_t)ND*4;
static const size_t OFF_RM  = OFF_SH  + (size_t)ND*4;
static const size_t OFF_RI  = OFF_RM  + (size_t)NB*4;
static const size_t OFF_HA  = OFF_RI  + (size_t)NB*4;
static const size_t OFF_RU  = OFF_HA  + (size_t)NB*4;
static const size_t OFF_ZP  = OFF_RU  + 128;                 // 128B zero pad (16B aligned)

__device__ __forceinline__ float uh2f(ushort u) {
    _Float16 h = __builtin_bit_cast(_Float16, u);
    return (float)h;
}
__device__ __forceinline__ ushort f2uh(float f) {
    _Float16 h = (_Float16)f;
    return __builtin_bit_cast(ushort, h);
}
__device__ __forceinline__ void load_lds16(const void* g, void* l) {
    __builtin_amdgcn_global_load_lds((const __attribute__((address_space(1))) void*)g,
                                     (__attribute__((address_space(3))) void*)l, 16, 0, 0);
}

// ---------------- split fp32 x -> (hi, lo) f16 planes ----------------
__global__ void k_split(const float* __restrict__ x, ushort* __restrict__ hi, ushort* __restrict__ lo)
{
    size_t i = ((size_t)blockIdx.x * 256 + threadIdx.x) * 4;
    float4 v = *(const float4*)(x + i);
    ushort4 h, l;
    h.x = f2uh(v.x); l.x = f2uh(v.x - uh2f(h.x));
    h.y = f2uh(v.y); l.y = f2uh(v.y - uh2f(h.y));
    h.z = f2uh(v.z); l.z = f2uh(v.z - uh2f(h.z));
    h.w = f2uh(v.w); l.w = f2uh(v.w - uh2f(h.w));
    *(ushort4*)(hi + i) = h;
    *(ushort4*)(lo + i) = l;
}

// ---------------- init: pack W (hi/lo, [dout][t][din]), BN affine, q, halted, running, zpad
__global__ void k_init(const float* __restrict__ conv_w, const float* __restrict__ conv_b,
                       const float* __restrict__ bn_gamma, const float* __restrict__ bn_beta,
                       const float* __restrict__ bn_mean, const float* __restrict__ bn_var,
                       const float* __restrict__ query,
                       ushort* __restrict__ Wph, ushort* __restrict__ Wpl,
                       float* __restrict__ scale, float* __restrict__ shift,
                       float* __restrict__ q, int* __restrict__ halted, int* __restrict__ running,
                       ushort* __restrict__ zpad)
{
    int idx = blockIdx.x * 256 + threadIdx.x;
    if (idx < 1280 * 256) {
        int din  = idx & 255;
        int r    = idx >> 8;
        int t    = r % 5;
        int dout = r / 5;
        float w = conv_w[dout * 1280 + din * 5 + t];
        ushort wh = f2uh(w);
        Wph[idx] = wh;
        Wpl[idx] = f2uh(w - uh2f(wh));
    }
    if (idx < NB * ND) q[idx] = query[idx & (ND - 1)];
    if (idx < ND) {
        float a = bn_gamma[idx] * rsqrtf(bn_var[idx] + EPSBN);
        scale[idx] = a;
        shift[idx] = (conv_b[idx] - bn_mean[idx]) * a + bn_beta[idx];
    }
    if (idx < 128) zpad[idx] = 0;
    if (idx < NB) halted[idx] = 0;
    if (idx == 0) running[0] = 1;
}

// ---------------- K1: e[b,s] = dot(x[b,s,:], q[b,:]) (hi+lo), mask -> -inf ----------------
__global__ void k_attn(const ushort* __restrict__ xhi, const ushort* __restrict__ xlo,
                       const float* __restrict__ q, const int* __restrict__ mask,
                       float* __restrict__ e)
{
    int row  = blockIdx.x * 4 + (threadIdx.x >> 6);
    int lane = threadIdx.x & 63;
    int b    = row >> 12;
    size_t o = (size_t)row * ND + (lane << 2);
    ushort4 hv = *(const ushort4*)(xhi + o);
    ushort4 lv = *(const ushort4*)(xlo + o);
    float4 qv = *(const float4*)(q + b * ND + (lane << 2));
    float v = (uh2f(hv.x) + uh2f(lv.x)) * qv.x
            + (uh2f(hv.y) + uh2f(lv.y)) * qv.y
            + (uh2f(hv.z) + uh2f(lv.z)) * qv.z
            + (uh2f(hv.w) + uh2f(lv.w)) * qv.w;
    #pragma unroll
    for (int off = 32; off; off >>= 1) v += __shfl_xor(v, off, 64);
    if (lane == 0) e[row] = (mask[row] != 0) ? -INFINITY : v;
}

// ---------------- K2: per-b softmax stats; block0 computes running flag ----------------
__global__ void k_stats(const float* __restrict__ e, float* __restrict__ rmax,
                        float* __restrict__ rinv, const int* __restrict__ halted,
                        int* __restrict__ running)
{
    __shared__ float sm[256];
    int b = blockIdx.x, tid = threadIdx.x;
    float m = -INFINITY;
    for (int s = tid; s < NS; s += 256) m = fmaxf(m, e[b * NS + s]);
    sm[tid] = m; __syncthreads();
    for (int off = 128; off; off >>= 1) {
        if (tid < off) sm[tid] = fmaxf(sm[tid], sm[tid + off]);
        __syncthreads();
    }
    float bm = sm[0]; __syncthreads();
    float sum = 0.f;
    for (int s = tid; s < NS; s += 256) sum += expf(e[b * NS + s] - bm);
    sm[tid] = sum; __syncthreads();
    for (int off = 128; off; off >>= 1) {
        if (tid < off) sm[tid] += sm[tid + off];
        __syncthreads();
    }
    if (tid == 0) { rmax[b] = bm; rinv[b] = 1.0f / sm[0]; }
    if (b == 0 && tid < 64) {
        unsigned long long any = __ballot(tid < NB && halted[tid] != 0);
        if (tid == 0) running[0] = (any == 0ull) ? 1 : 0;
    }
}

// ---------------- K3: conv via split-f16 MFMA, double-buffered LDS pipeline ----------------
// block 256 thr = 4 waves; tile 128 rows x 256 douts; wave = 128 rows x 64 douts
// (M_rep=8, N_rep=4 of 16x16x32). Round-3 register layout (128 VGPR + 128 AGPR, no spill).
// T3 2-phase: issue next chunk's global_load_lds BEFORE compute, vmcnt(0)+raw barrier AFTER.
// Boundary rows read from a zeroed global pad (no LDS zeroing in pipeline).
__global__ __launch_bounds__(256, 2) void k_conv(
    const ushort* __restrict__ xhi, const ushort* __restrict__ xlo,
    ushort* __restrict__ ohi, ushort* __restrict__ olo,
    const ushort* __restrict__ Wph, const ushort* __restrict__ Wpl,
    const float* __restrict__ scale, const float* __restrict__ shift,
    const int* __restrict__ maskp, const float* __restrict__ e,
    const float* __restrict__ rmax, const float* __restrict__ rinv,
    float* __restrict__ o_part, const ushort* __restrict__ zpad,
    const int* __restrict__ running)
{
    const int bb  = blockIdx.x >> 5;
    const int s0  = (blockIdx.x & 31) << 7;
    const int tid = threadIdx.x;

    if (running[0] == 0) {   // frozen: copy state (o_part stale but unused downstream)
        const size_t base = ((size_t)bb * NS + s0) * ND;
        const uint4* sh_ = (const uint4*)(xhi + base);
        const uint4* sl_ = (const uint4*)(xlo + base);
        uint4* dh = (uint4*)(ohi + base);
        uint4* dl = (uint4*)(olo + base);
        for (int i = tid; i < 4096; i += 256) { dh[i] = sh_[i]; dl[i] = sl_[i]; }
        return;
    }

    // dbuf: [buf][Ah 17408B | Al 17408B]; 136 rows x 64 din per plane
    __shared__ __align__(16) char ldsA[2 * 34816];
    __shared__ float p_lds[128];

    const int lane  = tid & 63;
    const int wid   = tid >> 6;
    const int mlane = lane & 15;       // C col / A row lane
    const int klane = lane >> 4;       // k-block
    const int dbase = wid << 6;        // wave's dout base

    // probs for this block's 128 rows (softmax of e over current xc)
    if (tid < 128) {
        float ev = e[bb * NS + s0 + tid];
        p_lds[tid] = expf(ev - rmax[bb]) * rinv[bb];
    }

    floatx4 acc[8][4];
    #pragma unroll
    for (int m = 0; m < 8; ++m)
        #pragma unroll
        for (int n = 0; n < 4; ++n) acc[m][n] = (floatx4){0.f, 0.f, 0.f, 0.f};

    // per-n W base pointers (dout fixed per lane) — round-3 proven layout
    const ushort* pWh[4];
    const ushort* pWl[4];
    #pragma unroll
    for (int n = 0; n < 4; ++n) {
        int dout = dbase + (n << 4) + mlane;
        pWh[n] = Wph + (size_t)dout * 1280;
        pWl[n] = Wpl + (size_t)dout * 1280;
    }

    // stage chunk kc (64 din) into buffer buf; LDS linear dest, pre-swizzled global src;
    // out-of-range rows pull 16B of zeros from zpad.
    auto STAGE = [&](int buf, int kc) {
        char* bh_ = ldsA + (size_t)buf * 34816;
        char* bl_ = bh_ + 17408;
        for (int i0 = tid; i0 < 1088; i0 += 256) {
            int lrow = i0 >> 3;
            int grp  = (i0 & 7) ^ (lrow & 7);
            int srow = s0 - 2 + lrow;
            const ushort* ph;
            const ushort* pl;
            if (srow >= 0 && srow < NS) {
                size_t go = ((size_t)bb * NS + srow) * ND + (kc << 6) + (grp << 3);
                ph = xhi + go; pl = xlo + go;
            } else {
                ph = zpad + (grp << 3); pl = zpad + (grp << 3);
            }
            load_lds16(ph, bh_ + i0 * 16);
            load_lds16(pl, bl_ + i0 * 16);
        }
    };

    // prologue
    STAGE(0, 0);
    asm volatile("s_waitcnt vmcnt(0) lgkmcnt(0)" ::: "memory");
    __builtin_amdgcn_s_barrier();
    asm volatile("" ::: "memory");

    for (int kc = 0; kc < 4; ++kc) {
        const int cur = kc & 1;
        if (kc < 3) STAGE(cur ^ 1, kc + 1);   // prefetch next chunk into other buffer

        const char* Ah = ldsA + cur * 34816;
        const char* Al = Ah + 17408;

        #pragma unroll
        for (int t = 0; t < 5; ++t) {
            #pragma unroll
            for (int ds_ = 0; ds_ < 2; ++ds_) {
                half8 bh[4], bl[4];
                const int din = (kc << 6) + (ds_ << 5) + (klane << 3);
                #pragma unroll
                for (int n = 0; n < 4; ++n) {
                    bh[n] = *(const half8*)(pWh[n] + t * 256 + din);
                    bl[n] = *(const half8*)(pWl[n] + t * 256 + din);
                }
                const int gb = (ds_ << 2) + klane;   // 16B group within 64-din row
                #pragma unroll
                for (int m = 0; m < 8; ++m) {
                    int row = (m << 4) + mlane + t;      // lds row = out_row + t
                    int off = (row << 7) + ((gb ^ (row & 7)) << 4);
                    half8 ah = *(const half8*)(Ah + off);
                    half8 al = *(const half8*)(Al + off);
                    #pragma unroll
                    for (int n = 0; n < 4; ++n) {
                        acc[m][n] = __builtin_amdgcn_mfma_f32_16x16x32_f16(ah, bh[n], acc[m][n], 0, 0, 0);
                        acc[m][n] = __builtin_amdgcn_mfma_f32_16x16x32_f16(ah, bl[n], acc[m][n], 0, 0, 0);
                        acc[m][n] = __builtin_amdgcn_mfma_f32_16x16x32_f16(al, bh[n], acc[m][n], 0, 0, 0);
                    }
                }
            }
        }

        // prefetched loads landed during compute; cheap drain + barrier flips buffers
        asm volatile("s_waitcnt vmcnt(0) lgkmcnt(0)" ::: "memory");
        __builtin_amdgcn_s_barrier();
        asm volatile("" ::: "memory");
    }

    // epilogue: BN + leakyReLU + mask, emit split f16, fused o partials
    float sc[4], sh[4];
    #pragma unroll
    for (int n = 0; n < 4; ++n) {
        int d = dbase + (n << 4) + mlane;
        sc[n] = scale[d]; sh[n] = shift[d];
    }
    float osum[4] = {0.f, 0.f, 0.f, 0.f};
    #pragma unroll
    for (int m = 0; m < 8; ++m) {
        #pragma unroll
        for (int r = 0; r < 4; ++r) {
            int prow = (m << 4) + (klane << 2) + r;  // C/D: row=(lane>>4)*4+reg
            int s = s0 + prow;
            int mk = maskp[bb * NS + s];
            float po = p_lds[prow];
            size_t ob = ((size_t)bb * NS + s) * ND + dbase + mlane;
            #pragma unroll
            for (int n = 0; n < 4; ++n) {
                float v = acc[m][n][r] * sc[n] + sh[n];
                v = (v >= 0.f) ? v : NEG_SLOPE * v;
                v = mk ? 0.f : v;
                ushort hw = f2uh(v);
                ushort lw = f2uh(v - uh2f(hw));
                ohi[ob + (size_t)(n << 4)] = hw;
                olo[ob + (size_t)(n << 4)] = lw;
                osum[n] += po * v;
            }
        }
    }
    // reduce over klane (lane bits 4,5); waves own disjoint douts -> direct global write
    #pragma unroll
    for (int n = 0; n < 4; ++n) {
        osum[n] += __shfl_xor(osum[n], 16, 64);
        osum[n] += __shfl_xor(osum[n], 32, 64);
    }
    if (lane < 16) {
        float* op = o_part + ((size_t)bb * 32 + (s0 >> 7)) * ND;
        #pragma unroll
        for (int n = 0; n < 4; ++n)
            op[dbase + (n << 4) + mlane] = osum[n];
    }
}

// ---------------- K5: reduce o, halt logits, gated q/halted update ----------------
__global__ void k_update(const float* __restrict__ o_part, float* __restrict__ q,
                         const float* __restrict__ halt_w, const float* __restrict__ halt_b,
                         int* __restrict__ halted, const int* __restrict__ running)
{
    int b = blockIdx.x, d = threadIdx.x;
    __shared__ float sh0[256], sh1[256];
    float o = 0.f;
    #pragma unroll
    for (int ch = 0; ch < 32; ++ch) o += o_part[(b * 32 + ch) * ND + d];
    float qd = q[b * ND + d];
    float s1 = o + qd;
    sh0[d] = s1 * halt_w[d];
    sh1[d] = s1 * halt_w[ND + d];
    __syncthreads();
    for (int off = 128; off; off >>= 1) {
        if (d < off) { sh0[d] += sh0[d + off]; sh1[d] += sh1[d + off]; }
        __syncthreads();
    }
    float l0 = sh0[0] + halt_b[0];
    float l1 = sh1[0] + halt_b[1];
    int hOld = halted[b];
    if (running[0]) {
        q[b * ND + d] = o + qd * (1.f - (float)hOld);
        if (d == 0) halted[b] = hOld | ((l1 > l0) ? 1 : 0);
    }
}

// ---------------- K6: q -> d_out ----------------
__global__ void k_copyout(const float* __restrict__ q, float* __restrict__ out)
{
    int idx = blockIdx.x * 256 + threadIdx.x;
    if (idx < NB * ND) out[idx] = q[idx];
}

extern "C" void kernel_launch(void* const* d_in, const int* in_sizes, int n_in,
                              void* d_out, int out_size, void* d_ws, size_t ws_size,
                              hipStream_t stream)
{
    const float* x        = (const float*)d_in[0];
    const int*   mask     = (const int*)  d_in[1];
    const float* query    = (const float*)d_in[2];
    const float* conv_w   = (const float*)d_in[3];
    const float* conv_b   = (const float*)d_in[4];
    const float* bn_gamma = (const float*)d_in[5];
    const float* bn_beta  = (const float*)d_in[6];
    const float* bn_mean  = (const float*)d_in[7];
    const float* bn_var   = (const float*)d_in[8];
    const float* halt_w   = (const float*)d_in[9];
    const float* halt_b   = (const float*)d_in[10];

    char* ws = (char*)d_ws;
    ushort* hi0 = (ushort*)(ws + OFF_HI0);
    ushort* lo0 = (ushort*)(ws + OFF_LO0);
    ushort* hi1 = (ushort*)(ws + OFF_HI1);
    ushort* lo1 = (ushort*)(ws + OFF_LO1);
    float* ebuf = (float*)(ws + OFF_E);
    float* qbuf = (float*)(ws + OFF_Q);
    float* opart= (float*)(ws + OFF_OP);
    ushort* Wph = (ushort*)(ws + OFF_WPH);
    ushort* Wpl = (ushort*)(ws + OFF_WPL);
    float* scale= (float*)(ws + OFF_SC);
    float* shift= (float*)(ws + OFF_SH);
    float* rmax = (float*)(ws + OFF_RM);
    float* rinv = (float*)(ws + OFF_RI);
    int* halted = (int*)  (ws + OFF_HA);
    int* runf   = (int*)  (ws + OFF_RU);
    ushort* zpad= (ushort*)(ws + OFF_ZP);

    k_init<<<1280, 256, 0, stream>>>(conv_w, conv_b, bn_gamma, bn_beta, bn_mean, bn_var,
                                     query, Wph, Wpl, scale, shift, qbuf, halted, runf, zpad);
    k_split<<<32768, 256, 0, stream>>>(x, hi0, lo0);

    for (int h = 0; h < NHOP; ++h) {
        const ushort* ih = (h & 1) ? hi1 : hi0;
        const ushort* il = (h & 1) ? lo1 : lo0;
        ushort* oh = (h & 1) ? hi0 : hi1;
        ushort* ol = (h & 1) ? lo0 : lo1;

        k_attn  <<<NB * NS / 4, 256, 0, stream>>>(ih, il, qbuf, mask, ebuf);
        k_stats <<<NB, 256, 0, stream>>>(ebuf, rmax, rinv, halted, runf);
        k_conv  <<<NB * 32, 256, 0, stream>>>(ih, il, oh, ol, Wph, Wpl, scale, shift,
                                              mask, ebuf, rmax, rinv, opart, zpad, runf);
        k_update<<<NB, 256, 0, stream>>>(opart, qbuf, halt_w, halt_b, halted, runf);
    }

    k_copyout<<<NB, 256, 0, stream>>>(qbuf, (float*)d_out);
}

// Round 7
// 2195.961 us; speedup vs baseline: 2.2273x; 1.1911x over previous
//
#include <hip/hip_runtime.h>
#include <hip/hip_bf16.h>
#include <math.h>

#define NB 32
#define NS 4096
#define ND 256
#define NHOP 10
#define EPSBN 1e-5f
#define NEG_SLOPE 0.01f

typedef _Float16 half8 __attribute__((ext_vector_type(8)));
typedef float floatx4 __attribute__((ext_vector_type(4)));

// ---------------- workspace layout (bytes) ----------------
static const size_t SZ_PAIR = (size_t)NB*NS*ND*2;            // 67,108,864 (ushort plane)
static const size_t OFF_HI0 = 0;
static const size_t OFF_LO0 = OFF_HI0 + SZ_PAIR;
static const size_t OFF_HI1 = OFF_LO0 + SZ_PAIR;
static const size_t OFF_LO1 = OFF_HI1 + SZ_PAIR;
static const size_t OFF_E   = OFF_LO1 + SZ_PAIR;
static const size_t OFF_Q   = OFF_E   + (size_t)NB*NS*4;
static const size_t OFF_OP  = OFF_Q   + (size_t)NB*ND*4;
static const size_t OFF_WPH = OFF_OP  + (size_t)NB*32*ND*4;
static const size_t OFF_WPL = OFF_WPH + (size_t)1280*ND*2;
static const size_t OFF_SC  = OFF_WPL + (size_t)1280*ND*2;
static const size_t OFF_SH  = OFF_SC  + (size_t)ND*4;
static const size_t OFF_RM  = OFF_SH  + (size_t)ND*4;
static const size_t OFF_RI  = OFF_RM  + (size_t)NB*4;
static const size_t OFF_HA  = OFF_RI  + (size_t)NB*4;
static const size_t OFF_RU  = OFF_HA  + (size_t)NB*4;
static const size_t OFF_ZP  = OFF_RU  + 128;                 // 128B zero pad (16B aligned)

__device__ __forceinline__ float uh2f(ushort u) {
    _Float16 h = __builtin_bit_cast(_Float16, u);
    return (float)h;
}
__device__ __forceinline__ ushort f2uh(float f) {
    _Float16 h = (_Float16)f;
    return __builtin_bit_cast(ushort, h);
}
__device__ __forceinline__ void load_lds16(const void* g, void* l) {
    __builtin_amdgcn_global_load_lds((const __attribute__((address_space(1))) void*)g,
                                     (__attribute__((address_space(3))) void*)l, 16, 0, 0);
}

// ---------------- split fp32 x -> (hi, lo) f16 planes ----------------
__global__ void k_split(const float* __restrict__ x, ushort* __restrict__ hi, ushort* __restrict__ lo)
{
    size_t i = ((size_t)blockIdx.x * 256 + threadIdx.x) * 4;
    float4 v = *(const float4*)(x + i);
    ushort4 h, l;
    h.x = f2uh(v.x); l.x = f2uh(v.x - uh2f(h.x));
    h.y = f2uh(v.y); l.y = f2uh(v.y - uh2f(h.y));
    h.z = f2uh(v.z); l.z = f2uh(v.z - uh2f(h.z));
    h.w = f2uh(v.w); l.w = f2uh(v.w - uh2f(h.w));
    *(ushort4*)(hi + i) = h;
    *(ushort4*)(lo + i) = l;
}

// ---------------- init: pack W (hi/lo), BN affine, q, halted, running, zpad ----------------
// W layout: idx = ((((kc*5 + t)*2 + ds)*256 + dout)*4 + kl)*8 + dj
//   where din = kc*64 + ds*32 + kl*8 + dj.  n-fragment stride (dout += 16) = 512 elem = 1024 B.
__global__ void k_init(const float* __restrict__ conv_w, const float* __restrict__ conv_b,
                       const float* __restrict__ bn_gamma, const float* __restrict__ bn_beta,
                       const float* __restrict__ bn_mean, const float* __restrict__ bn_var,
                       const float* __restrict__ query,
                       ushort* __restrict__ Wph, ushort* __restrict__ Wpl,
                       float* __restrict__ scale, float* __restrict__ shift,
                       float* __restrict__ q, int* __restrict__ halted, int* __restrict__ running,
                       ushort* __restrict__ zpad)
{
    int idx = blockIdx.x * 256 + threadIdx.x;
    if (idx < 1280 * 256) {
        int dj   = idx & 7;
        int kl   = (idx >> 3) & 3;
        int dout = (idx >> 5) & 255;
        int rest = idx >> 13;            // 0..39 = (kc*5 + t)*2 + ds
        int ds_  = rest & 1;
        int tkc  = rest >> 1;            // kc*5 + t
        int t    = tkc % 5;
        int kc   = tkc / 5;
        int din  = kc * 64 + ds_ * 32 + kl * 8 + dj;
        float w = conv_w[dout * 1280 + din * 5 + t];
        ushort wh = f2uh(w);
        Wph[idx] = wh;
        Wpl[idx] = f2uh(w - uh2f(wh));
    }
    if (idx < NB * ND) q[idx] = query[idx & (ND - 1)];
    if (idx < ND) {
        float a = bn_gamma[idx] * rsqrtf(bn_var[idx] + EPSBN);
        scale[idx] = a;
        shift[idx] = (conv_b[idx] - bn_mean[idx]) * a + bn_beta[idx];
    }
    if (idx < 128) zpad[idx] = 0;
    if (idx < NB) halted[idx] = 0;
    if (idx == 0) running[0] = 1;
}

// ---------------- K1: e[b,s] = dot(x[b,s,:], q[b,:]) (hi+lo), mask -> -inf ----------------
__global__ void k_attn(const ushort* __restrict__ xhi, const ushort* __restrict__ xlo,
                       const float* __restrict__ q, const int* __restrict__ mask,
                       float* __restrict__ e)
{
    int row  = blockIdx.x * 4 + (threadIdx.x >> 6);
    int lane = threadIdx.x & 63;
    int b    = row >> 12;
    size_t o = (size_t)row * ND + (lane << 2);
    ushort4 hv = *(const ushort4*)(xhi + o);
    ushort4 lv = *(const ushort4*)(xlo + o);
    float4 qv = *(const float4*)(q + b * ND + (lane << 2));
    float v = (uh2f(hv.x) + uh2f(lv.x)) * qv.x
            + (uh2f(hv.y) + uh2f(lv.y)) * qv.y
            + (uh2f(hv.z) + uh2f(lv.z)) * qv.z
            + (uh2f(hv.w) + uh2f(lv.w)) * qv.w;
    #pragma unroll
    for (int off = 32; off; off >>= 1) v += __shfl_xor(v, off, 64);
    if (lane == 0) e[row] = (mask[row] != 0) ? -INFINITY : v;
}

// ---------------- K2: per-b softmax stats; block0 computes running flag ----------------
__global__ void k_stats(const float* __restrict__ e, float* __restrict__ rmax,
                        float* __restrict__ rinv, const int* __restrict__ halted,
                        int* __restrict__ running)
{
    __shared__ float sm[256];
    int b = blockIdx.x, tid = threadIdx.x;
    float m = -INFINITY;
    for (int s = tid; s < NS; s += 256) m = fmaxf(m, e[b * NS + s]);
    sm[tid] = m; __syncthreads();
    for (int off = 128; off; off >>= 1) {
        if (tid < off) sm[tid] = fmaxf(sm[tid], sm[tid + off]);
        __syncthreads();
    }
    float bm = sm[0]; __syncthreads();
    float sum = 0.f;
    for (int s = tid; s < NS; s += 256) sum += expf(e[b * NS + s] - bm);
    sm[tid] = sum; __syncthreads();
    for (int off = 128; off; off >>= 1) {
        if (tid < off) sm[tid] += sm[tid + off];
        __syncthreads();
    }
    if (tid == 0) { rmax[b] = bm; rinv[b] = 1.0f / sm[0]; }
    if (b == 0 && tid < 64) {
        unsigned long long any = __ballot(tid < NB && halted[tid] != 0);
        if (tid == 0) running[0] = (any == 0ull) ? 1 : 0;
    }
}

// ---------------- K3: conv via split-f16 MFMA, dbuf LDS + B-frag software pipeline ---------
// block 256 thr = 4 waves; tile 128 rows x 256 douts; wave = 128 rows x 64 douts
// (M_rep=8, N_rep=4 of 16x16x32).  128 VGPR + 128 AGPR operating point (no spill).
// B-frags for step i+1 issued before step i's 96 MFMAs; W layout gives base + n*1024B.
__global__ __launch_bounds__(256, 2) void k_conv(
    const ushort* __restrict__ xhi, const ushort* __restrict__ xlo,
    ushort* __restrict__ ohi, ushort* __restrict__ olo,
    const ushort* __restrict__ Wph, const ushort* __restrict__ Wpl,
    const float* __restrict__ scale, const float* __restrict__ shift,
    const int* __restrict__ maskp, const float* __restrict__ e,
    const float* __restrict__ rmax, const float* __restrict__ rinv,
    float* __restrict__ o_part, const ushort* __restrict__ zpad,
    const int* __restrict__ running)
{
    const int bb  = blockIdx.x >> 5;
    const int s0  = (blockIdx.x & 31) << 7;
    const int tid = threadIdx.x;

    if (running[0] == 0) {   // frozen: copy state
        const size_t base = ((size_t)bb * NS + s0) * ND;
        const uint4* sh_ = (const uint4*)(xhi + base);
        const uint4* sl_ = (const uint4*)(xlo + base);
        uint4* dh = (uint4*)(ohi + base);
        uint4* dl = (uint4*)(olo + base);
        for (int i = tid; i < 4096; i += 256) { dh[i] = sh_[i]; dl[i] = sl_[i]; }
        return;
    }

    // dbuf: [buf][Ah 17408B | Al 17408B]; 136 rows x 64 din per plane
    __shared__ __align__(16) char ldsA[2 * 34816];
    __shared__ float p_lds[128];

    const int lane  = tid & 63;
    const int wid   = tid >> 6;
    const int mlane = lane & 15;       // C col / A row lane
    const int klane = lane >> 4;       // k-block
    const int dbase = wid << 6;        // wave's dout base

    if (tid < 128) {
        float ev = e[bb * NS + s0 + tid];
        p_lds[tid] = expf(ev - rmax[bb]) * rinv[bb];
    }

    floatx4 acc[8][4];
    #pragma unroll
    for (int m = 0; m < 8; ++m)
        #pragma unroll
        for (int n = 0; n < 4; ++n) acc[m][n] = (floatx4){0.f, 0.f, 0.f, 0.f};

    // lane-fixed element offset within a (kc,td) W slab
    const int laneoff = (dbase + mlane) * 32 + klane * 8;

    auto STAGE = [&](int buf, int kc) {
        char* bh_ = ldsA + (size_t)buf * 34816;
        char* bl_ = bh_ + 17408;
        for (int i0 = tid; i0 < 1088; i0 += 256) {
            int lrow = i0 >> 3;
            int grp  = (i0 & 7) ^ (lrow & 7);
            int srow = s0 - 2 + lrow;
            const ushort* ph;
            const ushort* pl;
            if (srow >= 0 && srow < NS) {
                size_t go = ((size_t)bb * NS + srow) * ND + (kc << 6) + (grp << 3);
                ph = xhi + go; pl = xlo + go;
            } else {
                ph = zpad + (grp << 3); pl = zpad + (grp << 3);
            }
            load_lds16(ph, bh_ + i0 * 16);
            load_lds16(pl, bl_ + i0 * 16);
        }
    };

    // prologue: stage chunk 0, preload B-frags for X=0
    STAGE(0, 0);
    half8 bh[4], bl[4], nbh[4], nbl[4];
    {
        const ushort* wb = Wph + laneoff;
        const ushort* wc = Wpl + laneoff;
        #pragma unroll
        for (int n = 0; n < 4; ++n) {
            bh[n] = *(const half8*)(wb + n * 512);
            bl[n] = *(const half8*)(wc + n * 512);
        }
    }
    asm volatile("s_waitcnt vmcnt(0) lgkmcnt(0)" ::: "memory");
    __builtin_amdgcn_s_barrier();
    asm volatile("" ::: "memory");

    for (int kc = 0; kc < 4; ++kc) {
        const int cur = kc & 1;
        if (kc < 3) STAGE(cur ^ 1, kc + 1);   // prefetch next chunk into other buffer

        const char* Ah = ldsA + cur * 34816;
        const char* Al = Ah + 17408;

        #pragma unroll
        for (int td = 0; td < 10; ++td) {     // td = t*2 + ds_
            const int X = kc * 10 + td;
            // ---- issue B-frag loads for step X+1 (land during this step's MFMAs) ----
            {
                const int Xn = (X < 39) ? X + 1 : 39;
                const ushort* wb = Wph + (size_t)Xn * 8192 + laneoff;
                const ushort* wc = Wpl + (size_t)Xn * 8192 + laneoff;
                #pragma unroll
                for (int n = 0; n < 4; ++n) {
                    nbh[n] = *(const half8*)(wb + n * 512);
                    nbl[n] = *(const half8*)(wc + n * 512);
                }
            }
            const int t   = td >> 1;
            const int ds_ = td & 1;
            const int gb  = (ds_ << 2) + klane;   // 16B group within 64-din row

            __builtin_amdgcn_s_setprio(1);
            #pragma unroll
            for (int m = 0; m < 8; ++m) {
                int row = (m << 4) + mlane + t;      // lds row = out_row + t
                int off = (row << 7) + ((gb ^ (row & 7)) << 4);
                half8 ah = *(const half8*)(Ah + off);
                half8 al = *(const half8*)(Al + off);
                #pragma unroll
                for (int n = 0; n < 4; ++n)
                    acc[m][n] = __builtin_amdgcn_mfma_f32_16x16x32_f16(ah, bh[n], acc[m][n], 0, 0, 0);
                #pragma unroll
                for (int n = 0; n < 4; ++n)
                    acc[m][n] = __builtin_amdgcn_mfma_f32_16x16x32_f16(ah, bl[n], acc[m][n], 0, 0, 0);
                #pragma unroll
                for (int n = 0; n < 4; ++n)
                    acc[m][n] = __builtin_amdgcn_mfma_f32_16x16x32_f16(al, bh[n], acc[m][n], 0, 0, 0);
            }
            __builtin_amdgcn_s_setprio(0);

            // rotate pipelined B-frags
            #pragma unroll
            for (int n = 0; n < 4; ++n) { bh[n] = nbh[n]; bl[n] = nbl[n]; }
        }

        asm volatile("s_waitcnt vmcnt(0) lgkmcnt(0)" ::: "memory");
        __builtin_amdgcn_s_barrier();
        asm volatile("" ::: "memory");
    }

    // epilogue: BN + leakyReLU + mask, emit split f16, fused o partials
    float sc[4], sh[4];
    #pragma unroll
    for (int n = 0; n < 4; ++n) {
        int d = dbase + (n << 4) + mlane;
        sc[n] = scale[d]; sh[n] = shift[d];
    }
    float osum[4] = {0.f, 0.f, 0.f, 0.f};
    #pragma unroll
    for (int m = 0; m < 8; ++m) {
        #pragma unroll
        for (int r = 0; r < 4; ++r) {
            int prow = (m << 4) + (klane << 2) + r;  // C/D: row=(lane>>4)*4+reg
            int s = s0 + prow;
            int mk = maskp[bb * NS + s];
            float po = p_lds[prow];
            size_t ob = ((size_t)bb * NS + s) * ND + dbase + mlane;
            #pragma unroll
            for (int n = 0; n < 4; ++n) {
                float v = acc[m][n][r] * sc[n] + sh[n];
                v = (v >= 0.f) ? v : NEG_SLOPE * v;
                v = mk ? 0.f : v;
                ushort hw = f2uh(v);
                ushort lw = f2uh(v - uh2f(hw));
                ohi[ob + (size_t)(n << 4)] = hw;
                olo[ob + (size_t)(n << 4)] = lw;
                osum[n] += po * v;
            }
        }
    }
    #pragma unroll
    for (int n = 0; n < 4; ++n) {
        osum[n] += __shfl_xor(osum[n], 16, 64);
        osum[n] += __shfl_xor(osum[n], 32, 64);
    }
    if (lane < 16) {
        float* op = o_part + ((size_t)bb * 32 + (s0 >> 7)) * ND;
        #pragma unroll
        for (int n = 0; n < 4; ++n)
            op[dbase + (n << 4) + mlane] = osum[n];
    }
}

// ---------------- K5: reduce o, halt logits, gated q/halted update ----------------
__global__ void k_update(const float* __restrict__ o_part, float* __restrict__ q,
                         const float* __restrict__ halt_w, const float* __restrict__ halt_b,
                         int* __restrict__ halted, const int* __restrict__ running)
{
    int b = blockIdx.x, d = threadIdx.x;
    __shared__ float sh0[256], sh1[256];
    float o = 0.f;
    #pragma unroll
    for (int ch = 0; ch < 32; ++ch) o += o_part[(b * 32 + ch) * ND + d];
    float qd = q[b * ND + d];
    float s1 = o + qd;
    sh0[d] = s1 * halt_w[d];
    sh1[d] = s1 * halt_w[ND + d];
    __syncthreads();
    for (int off = 128; off; off >>= 1) {
        if (d < off) { sh0[d] += sh0[d + off]; sh1[d] += sh1[d + off]; }
        __syncthreads();
    }
    float l0 = sh0[0] + halt_b[0];
    float l1 = sh1[0] + halt_b[1];
    int hOld = halted[b];
    if (running[0]) {
        q[b * ND + d] = o + qd * (1.f - (float)hOld);
        if (d == 0) halted[b] = hOld | ((l1 > l0) ? 1 : 0);
    }
}

// ---------------- K6: q -> d_out ----------------
__global__ void k_copyout(const float* __restrict__ q, float* __restrict__ out)
{
    int idx = blockIdx.x * 256 + threadIdx.x;
    if (idx < NB * ND) out[idx] = q[idx];
}

extern "C" void kernel_launch(void* const* d_in, const int* in_sizes, int n_in,
                              void* d_out, int out_size, void* d_ws, size_t ws_size,
                              hipStream_t stream)
{
    const float* x        = (const float*)d_in[0];
    const int*   mask     = (const int*)  d_in[1];
    const float* query    = (const float*)d_in[2];
    const float* conv_w   = (const float*)d_in[3];
    const float* conv_b   = (const float*)d_in[4];
    const float* bn_gamma = (const float*)d_in[5];
    const float* bn_beta  = (const float*)d_in[6];
    const float* bn_mean  = (const float*)d_in[7];
    const float* bn_var   = (const float*)d_in[8];
    const float* halt_w   = (const float*)d_in[9];
    const float* halt_b   = (const float*)d_in[10];

    char* ws = (char*)d_ws;
    ushort* hi0 = (ushort*)(ws + OFF_HI0);
    ushort* lo0 = (ushort*)(ws + OFF_LO0);
    ushort* hi1 = (ushort*)(ws + OFF_HI1);
    ushort* lo1 = (ushort*)(ws + OFF_LO1);
    float* ebuf = (float*)(ws + OFF_E);
    float* qbuf = (float*)(ws + OFF_Q);
    float* opart= (float*)(ws + OFF_OP);
    ushort* Wph = (ushort*)(ws + OFF_WPH);
    ushort* Wpl = (ushort*)(ws + OFF_WPL);
    float* scale= (float*)(ws + OFF_SC);
    float* shift= (float*)(ws + OFF_SH);
    float* rmax = (float*)(ws + OFF_RM);
    float* rinv = (float*)(ws + OFF_RI);
    int* halted = (int*)  (ws + OFF_HA);
    int* runf   = (int*)  (ws + OFF_RU);
    ushort* zpad= (ushort*)(ws + OFF_ZP);

    k_init<<<1280, 256, 0, stream>>>(conv_w, conv_b, bn_gamma, bn_beta, bn_mean, bn_var,
                                     query, Wph, Wpl, scale, shift, qbuf, halted, runf, zpad);
    k_split<<<32768, 256, 0, stream>>>(x, hi0, lo0);

    for (int h = 0; h < NHOP; ++h) {
        const ushort* ih = (h & 1) ? hi1 : hi0;
        const ushort* il = (h & 1) ? lo1 : lo0;
        ushort* oh = (h & 1) ? hi0 : hi1;
        ushort* ol = (h & 1) ? lo0 : lo1;

        k_attn  <<<NB * NS / 4, 256, 0, stream>>>(ih, il, qbuf, mask, ebuf);
        k_stats <<<NB, 256, 0, stream>>>(ebuf, rmax, rinv, halted, runf);
        k_conv  <<<NB * 32, 256, 0, stream>>>(ih, il, oh, ol, Wph, Wpl, scale, shift,
                                              mask, ebuf, rmax, rinv, opart, zpad, runf);
        k_update<<<NB, 256, 0, stream>>>(opart, qbuf, halt_w, halt_b, halted, runf);
    }

    k_copyout<<<NB, 256, 0, stream>>>(qbuf, (float*)d_out);
}

// Round 9
// 2040.177 us; speedup vs baseline: 2.3974x; 1.0764x over previous
//
#include <hip/hip_runtime.h>
#include <hip/hip_bf16.h>
#include <math.h>

#define NB 32
#define NS 4096
#define ND 256
#define NHOP 10
#define EPSBN 1e-5f
#define NEG_SLOPE 0.01f

typedef _Float16 half8 __attribute__((ext_vector_type(8)));
typedef float floatx4 __attribute__((ext_vector_type(4)));

// ---------------- workspace layout (bytes) ----------------
static const size_t SZ_PAIR = (size_t)NB*NS*ND*2;            // 67,108,864 (ushort plane)
static const size_t OFF_HI0 = 0;
static const size_t OFF_LO0 = OFF_HI0 + SZ_PAIR;
static const size_t OFF_HI1 = OFF_LO0 + SZ_PAIR;
static const size_t OFF_LO1 = OFF_HI1 + SZ_PAIR;
static const size_t OFF_MP  = OFF_LO1 + SZ_PAIR;             // m_part [NB*32]
static const size_t OFF_LP  = OFF_MP  + (size_t)NB*32*4;     // l_part [NB*32]
static const size_t OFF_Q   = OFF_LP  + (size_t)NB*32*4;
static const size_t OFF_OP  = OFF_Q   + (size_t)NB*ND*4;
static const size_t OFF_WPH = OFF_OP  + (size_t)NB*32*ND*4;
static const size_t OFF_WPL = OFF_WPH + (size_t)1280*ND*2;
static const size_t OFF_SC  = OFF_WPL + (size_t)1280*ND*2;
static const size_t OFF_SH  = OFF_SC  + (size_t)ND*4;
static const size_t OFF_HA  = OFF_SH  + (size_t)ND*4;        // halted buf A [NB]
static const size_t OFF_HB  = OFF_HA  + 128;                 // halted buf B [NB]
static const size_t OFF_ZP  = OFF_HB  + 128;                 // 128B zero pad (16B aligned)

__device__ __forceinline__ float uh2f(ushort u) {
    _Float16 h = __builtin_bit_cast(_Float16, u);
    return (float)h;
}
__device__ __forceinline__ ushort f2uh(float f) {
    _Float16 h = (_Float16)f;
    return __builtin_bit_cast(ushort, h);
}
__device__ __forceinline__ void load_lds16(const void* g, void* l) {
    __builtin_amdgcn_global_load_lds((const __attribute__((address_space(1))) void*)g,
                                     (__attribute__((address_space(3))) void*)l, 16, 0, 0);
}

// ---------------- split fp32 x -> (hi, lo) f16 planes ----------------
__global__ void k_split(const float* __restrict__ x, ushort* __restrict__ hi, ushort* __restrict__ lo)
{
    size_t i = ((size_t)blockIdx.x * 256 + threadIdx.x) * 4;
    float4 v = *(const float4*)(x + i);
    ushort4 h, l;
    h.x = f2uh(v.x); l.x = f2uh(v.x - uh2f(h.x));
    h.y = f2uh(v.y); l.y = f2uh(v.y - uh2f(h.y));
    h.z = f2uh(v.z); l.z = f2uh(v.z - uh2f(h.z));
    h.w = f2uh(v.w); l.w = f2uh(v.w - uh2f(h.w));
    *(ushort4*)(hi + i) = h;
    *(ushort4*)(lo + i) = l;
}

// ---------------- init: pack W (hi/lo), BN affine, q, halted bufs, zpad ----------------
// W layout: idx = ((((kc*5 + t)*2 + ds)*256 + dout)*4 + kl)*8 + dj
//   where din = kc*64 + ds*32 + kl*8 + dj.  n-fragment stride (dout += 16) = 512 elem = 1024 B.
__global__ void k_init(const float* __restrict__ conv_w, const float* __restrict__ conv_b,
                       const float* __restrict__ bn_gamma, const float* __restrict__ bn_beta,
                       const float* __restrict__ bn_mean, const float* __restrict__ bn_var,
                       const float* __restrict__ query,
                       ushort* __restrict__ Wph, ushort* __restrict__ Wpl,
                       float* __restrict__ scale, float* __restrict__ shift,
                       float* __restrict__ q, int* __restrict__ hA, int* __restrict__ hB,
                       ushort* __restrict__ zpad)
{
    int idx = blockIdx.x * 256 + threadIdx.x;
    if (idx < 1280 * 256) {
        int dj   = idx & 7;
        int kl   = (idx >> 3) & 3;
        int dout = (idx >> 5) & 255;
        int rest = idx >> 13;            // 0..39 = (kc*5 + t)*2 + ds
        int ds_  = rest & 1;
        int tkc  = rest >> 1;            // kc*5 + t
        int t    = tkc % 5;
        int kc   = tkc / 5;
        int din  = kc * 64 + ds_ * 32 + kl * 8 + dj;
        float w = conv_w[dout * 1280 + din * 5 + t];
        ushort wh = f2uh(w);
        Wph[idx] = wh;
        Wpl[idx] = f2uh(w - uh2f(wh));
    }
    if (idx < NB * ND) q[idx] = query[idx & (ND - 1)];
    if (idx < ND) {
        float a = bn_gamma[idx] * rsqrtf(bn_var[idx] + EPSBN);
        scale[idx] = a;
        shift[idx] = (conv_b[idx] - bn_mean[idx]) * a + bn_beta[idx];
    }
    if (idx < 128) zpad[idx] = 0;
    if (idx < NB) { hA[idx] = 0; hB[idx] = 0; }
}

// ---------------- K3: conv + inline attention-e + flash softmax partials -------------------
// block 256 thr = 4 waves; tile 128 rows x 256 douts; wave = 128 rows x 64 douts
// (M_rep=8, N_rep=4 of 16x16x32).  128 VGPR + 128 AGPR operating point.
// Per kc chunk: stage next chunk (dbuf), accumulate e-rows from staged LDS (tid<128),
// B-frag software pipeline one td-step ahead.  End: block-local softmax (m_blk, L~),
// unnormalized p~ weights the fused o-partials; k_update does the flash combine.
__global__ __launch_bounds__(256, 2) void k_conv(
    const ushort* __restrict__ xhi, const ushort* __restrict__ xlo,
    ushort* __restrict__ ohi, ushort* __restrict__ olo,
    const ushort* __restrict__ Wph, const ushort* __restrict__ Wpl,
    const float* __restrict__ scale, const float* __restrict__ shift,
    const int* __restrict__ maskp, const float* __restrict__ q,
    float* __restrict__ o_part, float* __restrict__ m_part, float* __restrict__ l_part,
    const ushort* __restrict__ zpad, const int* __restrict__ halted)
{
    const int bb  = blockIdx.x >> 5;
    const int s0  = (blockIdx.x & 31) << 7;
    const int tid = threadIdx.x;
    const int lane  = tid & 63;

    // running = !any(halted), computed per-wave (uniform across block; halted is
    // read-only for this dispatch -> no intra-dispatch race)
    {
        int hv = (lane < NB) ? halted[lane] : 0;
        unsigned long long bl = __ballot(hv != 0);
        if (bl != 0ull) {   // frozen: copy state
            const size_t base = ((size_t)bb * NS + s0) * ND;
            const uint4* sh_ = (const uint4*)(xhi + base);
            const uint4* sl_ = (const uint4*)(xlo + base);
            uint4* dh = (uint4*)(ohi + base);
            uint4* dl = (uint4*)(olo + base);
            for (int i = tid; i < 4096; i += 256) { dh[i] = sh_[i]; dl[i] = sl_[i]; }
            return;
        }
    }

    // dbuf: [buf][Ah 17408B | Al 17408B]; 136 rows x 64 din per plane
    __shared__ __align__(16) char ldsA[2 * 34816];
    __shared__ float p_lds[128];
    __shared__ float red[128];
    __shared__ float s_mblk, s_lsum;

    const int wid   = tid >> 6;
    const int mlane = lane & 15;       // C col / A row lane
    const int klane = lane >> 4;       // k-block
    const int dbase = wid << 6;        // wave's dout base

    // per-row mask + e accumulator (rows owned by tid<128)
    const int msk_row = (tid < 128) ? maskp[bb * NS + s0 + tid] : 1;
    float e_acc = 0.f;

    floatx4 acc[8][4];
    #pragma unroll
    for (int m = 0; m < 8; ++m)
        #pragma unroll
        for (int n = 0; n < 4; ++n) acc[m][n] = (floatx4){0.f, 0.f, 0.f, 0.f};

    // lane-fixed element offset within a (kc,td) W slab
    const int laneoff = (dbase + mlane) * 32 + klane * 8;

    auto STAGE = [&](int buf, int kc) {
        char* bh_ = ldsA + (size_t)buf * 34816;
        char* bl_ = bh_ + 17408;
        for (int i0 = tid; i0 < 1088; i0 += 256) {
            int lrow = i0 >> 3;
            int grp  = (i0 & 7) ^ (lrow & 7);
            int srow = s0 - 2 + lrow;
            const ushort* ph;
            const ushort* pl;
            if (srow >= 0 && srow < NS) {
                size_t go = ((size_t)bb * NS + srow) * ND + (kc << 6) + (grp << 3);
                ph = xhi + go; pl = xlo + go;
            } else {
                ph = zpad + (grp << 3); pl = zpad + (grp << 3);
            }
            load_lds16(ph, bh_ + i0 * 16);
            load_lds16(pl, bl_ + i0 * 16);
        }
    };

    // prologue: stage chunk 0, preload B-frags for X=0
    STAGE(0, 0);
    half8 bh[4], bl[4], nbh[4], nbl[4];
    {
        const ushort* wb = Wph + laneoff;
        const ushort* wc = Wpl + laneoff;
        #pragma unroll
        for (int n = 0; n < 4; ++n) {
            bh[n] = *(const half8*)(wb + n * 512);
            bl[n] = *(const half8*)(wc + n * 512);
        }
    }
    asm volatile("s_waitcnt vmcnt(0) lgkmcnt(0)" ::: "memory");
    __builtin_amdgcn_s_barrier();
    asm volatile("" ::: "memory");

    for (int kc = 0; kc < 4; ++kc) {
        const int cur = kc & 1;
        if (kc < 3) STAGE(cur ^ 1, kc + 1);   // prefetch next chunk into other buffer

        const char* Ah = ldsA + cur * 34816;
        const char* Al = Ah + 17408;

        // ---- inline attention dot for this chunk: e_row += x[row, kc*64..+64] . q ----
        if (tid < 128 && !msk_row) {
            const int lrow = tid + 2;
            const int rs = lrow & 7;
            const float* qp = q + bb * ND + (kc << 6);
            float ea = 0.f;
            #pragma unroll
            for (int g = 0; g < 8; ++g) {
                int off = (lrow << 7) + ((g ^ rs) << 4);
                half8 hh = *(const half8*)(Ah + off);
                half8 ll = *(const half8*)(Al + off);
                float4 q0 = *(const float4*)(qp + g * 8);
                float4 q1 = *(const float4*)(qp + g * 8 + 4);
                ea += ((float)hh[0] + (float)ll[0]) * q0.x;
                ea += ((float)hh[1] + (float)ll[1]) * q0.y;
                ea += ((float)hh[2] + (float)ll[2]) * q0.z;
                ea += ((float)hh[3] + (float)ll[3]) * q0.w;
                ea += ((float)hh[4] + (float)ll[4]) * q1.x;
                ea += ((float)hh[5] + (float)ll[5]) * q1.y;
                ea += ((float)hh[6] + (float)ll[6]) * q1.z;
                ea += ((float)hh[7] + (float)ll[7]) * q1.w;
            }
            e_acc += ea;
        }

        #pragma unroll
        for (int td = 0; td < 10; ++td) {     // td = t*2 + ds_
            const int X = kc * 10 + td;
            // ---- issue B-frag loads for step X+1 (land during this step's MFMAs) ----
            {
                const int Xn = (X < 39) ? X + 1 : 39;
                const ushort* wb = Wph + (size_t)Xn * 8192 + laneoff;
                const ushort* wc = Wpl + (size_t)Xn * 8192 + laneoff;
                #pragma unroll
                for (int n = 0; n < 4; ++n) {
                    nbh[n] = *(const half8*)(wb + n * 512);
                    nbl[n] = *(const half8*)(wc + n * 512);
                }
            }
            const int t   = td >> 1;
            const int ds_ = td & 1;
            const int gb  = (ds_ << 2) + klane;   // 16B group within 64-din row

            __builtin_amdgcn_s_setprio(1);
            #pragma unroll
            for (int m = 0; m < 8; ++m) {
                int row = (m << 4) + mlane + t;      // lds row = out_row + t
                int off = (row << 7) + ((gb ^ (row & 7)) << 4);
                half8 ah = *(const half8*)(Ah + off);
                half8 al = *(const half8*)(Al + off);
                #pragma unroll
                for (int n = 0; n < 4; ++n)
                    acc[m][n] = __builtin_amdgcn_mfma_f32_16x16x32_f16(ah, bh[n], acc[m][n], 0, 0, 0);
                #pragma unroll
                for (int n = 0; n < 4; ++n)
                    acc[m][n] = __builtin_amdgcn_mfma_f32_16x16x32_f16(ah, bl[n], acc[m][n], 0, 0, 0);
                #pragma unroll
                for (int n = 0; n < 4; ++n)
                    acc[m][n] = __builtin_amdgcn_mfma_f32_16x16x32_f16(al, bh[n], acc[m][n], 0, 0, 0);
            }
            __builtin_amdgcn_s_setprio(0);

            // rotate pipelined B-frags
            #pragma unroll
            for (int n = 0; n < 4; ++n) { bh[n] = nbh[n]; bl[n] = nbl[n]; }
        }

        asm volatile("s_waitcnt vmcnt(0) lgkmcnt(0)" ::: "memory");
        __builtin_amdgcn_s_barrier();
        asm volatile("" ::: "memory");
    }

    // ---- block-local softmax: m_blk = max(e), p~ = exp(e - m_blk), L~ = sum(p~) ----
    if (tid < 128) red[tid] = msk_row ? -INFINITY : e_acc;
    __syncthreads();
    if (tid < 64) {
        float v = fmaxf(red[tid], red[tid + 64]);
        #pragma unroll
        for (int off = 32; off; off >>= 1) v = fmaxf(v, __shfl_xor(v, off, 64));
        if (tid == 0) s_mblk = v;
    }
    __syncthreads();
    const float mb = s_mblk;
    if (tid < 128) {
        float pt = msk_row ? 0.f : expf(e_acc - mb);
        p_lds[tid] = pt;
        red[tid] = pt;
    }
    __syncthreads();
    if (tid < 64) {
        float v = red[tid] + red[tid + 64];
        #pragma unroll
        for (int off = 32; off; off >>= 1) v += __shfl_xor(v, off, 64);
        if (tid == 0) s_lsum = v;
    }
    __syncthreads();
    if (tid == 0) {
        m_part[bb * 32 + (s0 >> 7)] = mb;
        l_part[bb * 32 + (s0 >> 7)] = s_lsum;
    }

    // epilogue: BN + leakyReLU + mask, emit split f16, fused (unnormalized) o partials
    float sc[4], sh[4];
    #pragma unroll
    for (int n = 0; n < 4; ++n) {
        int d = dbase + (n << 4) + mlane;
        sc[n] = scale[d]; sh[n] = shift[d];
    }
    float osum[4] = {0.f, 0.f, 0.f, 0.f};
    #pragma unroll
    for (int m = 0; m < 8; ++m) {
        #pragma unroll
        for (int r = 0; r < 4; ++r) {
            int prow = (m << 4) + (klane << 2) + r;  // C/D: row=(lane>>4)*4+reg
            int s = s0 + prow;
            int mk = maskp[bb * NS + s];
            float po = p_lds[prow];
            size_t ob = ((size_t)bb * NS + s) * ND + dbase + mlane;
            #pragma unroll
            for (int n = 0; n < 4; ++n) {
                float v = acc[m][n][r] * sc[n] + sh[n];
                v = (v >= 0.f) ? v : NEG_SLOPE * v;
                v = mk ? 0.f : v;
                ushort hw = f2uh(v);
                ushort lw = f2uh(v - uh2f(hw));
                ohi[ob + (size_t)(n << 4)] = hw;
                olo[ob + (size_t)(n << 4)] = lw;
                osum[n] += po * v;
            }
        }
    }
    #pragma unroll
    for (int n = 0; n < 4; ++n) {
        osum[n] += __shfl_xor(osum[n], 16, 64);
        osum[n] += __shfl_xor(osum[n], 32, 64);
    }
    if (lane < 16) {
        float* op = o_part + ((size_t)bb * 32 + (s0 >> 7)) * ND;
        #pragma unroll
        for (int n = 0; n < 4; ++n)
            op[dbase + (n << 4) + mlane] = osum[n];
    }
}

// ---------------- K5: flash combine o, halt logits, gated q update ----------------
// Reads hIn (previous hop's halted state), writes hOut — no intra-dispatch race.
__global__ void k_update(const float* __restrict__ o_part, const float* __restrict__ m_part,
                         const float* __restrict__ l_part, float* __restrict__ q,
                         const float* __restrict__ halt_w, const float* __restrict__ halt_b,
                         const int* __restrict__ hIn, int* __restrict__ hOut)
{
    int b = blockIdx.x, d = threadIdx.x;
    int lane = d & 63;
    // running = !any(halted) BEFORE this step's update
    int hv = (lane < NB) ? hIn[lane] : 0;
    unsigned long long bl = __ballot(hv != 0);
    int running = (bl == 0ull) ? 1 : 0;

    __shared__ float w[33];
    __shared__ float sh0[256], sh1[256];
    if (d == 0) {
        float M = -INFINITY;
        for (int ch = 0; ch < 32; ++ch) M = fmaxf(M, m_part[b * 32 + ch]);
        float S = 0.f;
        for (int ch = 0; ch < 32; ++ch) {
            float wv = expf(m_part[b * 32 + ch] - M);
            w[ch] = wv;
            S += wv * l_part[b * 32 + ch];
        }
        w[32] = 1.0f / S;
    }
    __syncthreads();
    float o = 0.f;
    #pragma unroll
    for (int ch = 0; ch < 32; ++ch) o += w[ch] * o_part[(b * 32 + ch) * ND + d];
    o *= w[32];

    float qd = q[b * ND + d];
    float s1 = o + qd;
    sh0[d] = s1 * halt_w[d];
    sh1[d] = s1 * halt_w[ND + d];
    __syncthreads();
    for (int off = 128; off; off >>= 1) {
        if (d < off) { sh0[d] += sh0[d + off]; sh1[d] += sh1[d + off]; }
        __syncthreads();
    }
    float l0 = sh0[0] + halt_b[0];
    float l1 = sh1[0] + halt_b[1];
    int hOld = hIn[b];
    if (running) {
        q[b * ND + d] = o + qd * (1.f - (float)hOld);
        if (d == 0) hOut[b] = hOld | ((l1 > l0) ? 1 : 0);
    } else {
        if (d == 0) hOut[b] = hOld;
    }
}

// ---------------- K6: q -> d_out ----------------
__global__ void k_copyout(const float* __restrict__ q, float* __restrict__ out)
{
    int idx = blockIdx.x * 256 + threadIdx.x;
    if (idx < NB * ND) out[idx] = q[idx];
}

extern "C" void kernel_launch(void* const* d_in, const int* in_sizes, int n_in,
                              void* d_out, int out_size, void* d_ws, size_t ws_size,
                              hipStream_t stream)
{
    const float* x        = (const float*)d_in[0];
    const int*   mask     = (const int*)  d_in[1];
    const float* query    = (const float*)d_in[2];
    const float* conv_w   = (const float*)d_in[3];
    const float* conv_b   = (const float*)d_in[4];
    const float* bn_gamma = (const float*)d_in[5];
    const float* bn_beta  = (const float*)d_in[6];
    const float* bn_mean  = (const float*)d_in[7];
    const float* bn_var   = (const float*)d_in[8];
    const float* halt_w   = (const float*)d_in[9];
    const float* halt_b   = (const float*)d_in[10];

    char* ws = (char*)d_ws;
    ushort* hi0 = (ushort*)(ws + OFF_HI0);
    ushort* lo0 = (ushort*)(ws + OFF_LO0);
    ushort* hi1 = (ushort*)(ws + OFF_HI1);
    ushort* lo1 = (ushort*)(ws + OFF_LO1);
    float* mpart= (float*)(ws + OFF_MP);
    float* lpart= (float*)(ws + OFF_LP);
    float* qbuf = (float*)(ws + OFF_Q);
    float* opart= (float*)(ws + OFF_OP);
    ushort* Wph = (ushort*)(ws + OFF_WPH);
    ushort* Wpl = (ushort*)(ws + OFF_WPL);
    float* scale= (float*)(ws + OFF_SC);
    float* shift= (float*)(ws + OFF_SH);
    int* hA     = (int*)  (ws + OFF_HA);
    int* hB     = (int*)  (ws + OFF_HB);
    ushort* zpad= (ushort*)(ws + OFF_ZP);

    k_init<<<1280, 256, 0, stream>>>(conv_w, conv_b, bn_gamma, bn_beta, bn_mean, bn_var,
                                     query, Wph, Wpl, scale, shift, qbuf, hA, hB, zpad);
    k_split<<<32768, 256, 0, stream>>>(x, hi0, lo0);

    for (int h = 0; h < NHOP; ++h) {
        const ushort* ih = (h & 1) ? hi1 : hi0;
        const ushort* il = (h & 1) ? lo1 : lo0;
        ushort* oh = (h & 1) ? hi0 : hi1;
        ushort* ol = (h & 1) ? lo0 : lo1;
        const int* hIn = (h & 1) ? hB : hA;
        int*       hOut= (h & 1) ? hA : hB;

        k_conv  <<<NB * 32, 256, 0, stream>>>(ih, il, oh, ol, Wph, Wpl, scale, shift,
                                              mask, qbuf, opart, mpart, lpart, zpad, hIn);
        k_update<<<NB, 256, 0, stream>>>(opart, mpart, lpart, qbuf, halt_w, halt_b, hIn, hOut);
    }

    k_copyout<<<NB, 256, 0, stream>>>(qbuf, (float*)d_out);
}